// Round 7
// baseline (263.818 us; speedup 1.0000x reference)
//
#include <hip/hip_runtime.h>

#define BATCH 4
#define NPTS  4096
#define NQ    8192
#define KNN   20
#define RES   64
#define FDIM  6
#define BN    (BATCH * NPTS)       // 16384 points total

#define NSEG    4                  // candidate segments per batch
#define SEG     (NPTS / NSEG)      // 1024 candidates per segment
#define PPB     256                // points per block (filter)
#define PGROUPS (NPTS / PPB)       // 16

#define CAP 48                     // survivor capacity per (point, segment)
// r0 = cbrt(60 / (4096 * 4/3*pi)) : radius capturing ~60 expected neighbours interior
#define R0 0.15179f

// ---------------- ws layout ----------------
// [0, SD_BYTES)            : sd survivor d2 lists (12.6MB)   — aliases grid
// [SD_BYTES, +SI_BYTES)    : si survivor idx lists (6.3MB)   — aliases grid
//   (both consumed by select BEFORE the grid memset)
// [0, GRID_BYTES)          : grid (B,64,64,64,6) after memset
// [GRID_BYTES, +64K)       : cnt (NSEG*BN uchars), written unconditionally
// feat (B*NPTS*6 floats = 384KB) lives in the FRONT OF d_out: written by select,
// read by rasterize, then fully overwritten by interp's final output.
#define GRID_ELEMS ((size_t)BATCH * RES * RES * RES * FDIM)
#define GRID_BYTES (GRID_ELEMS * sizeof(float))                          // 25,165,824
#define SD_BYTES   ((size_t)NSEG * BN * CAP * sizeof(float))             // 12,582,912
#define SI_BYTES   ((size_t)NSEG * BN * CAP * sizeof(unsigned short))    //  6,291,456

__device__ __forceinline__ float dist2s(float cx, float cy, float cz,
                                        float px, float py, float pz) {
    float dx = cx - px, dy = cy - py, dz = cz - pz;
    return __builtin_fmaf(dz, dz, __builtin_fmaf(dy, dy, dx * dx));
}

// Branchless insert of pre-sorted pair (lo<=hi) into ascending 20-reg list.
#define PAIR_INSERT(d, lo, hi)                                   \
    _Pragma("unroll")                                            \
    for (int s = 0; s < KNN; ++s) {                              \
        float a_ = d[s];                                         \
        float mn_ = fminf(fminf(a_, lo), hi);                    \
        float md_ = __builtin_amdgcn_fmed3f(a_, lo, hi);         \
        float mx_ = fmaxf(fmaxf(a_, lo), hi);                    \
        d[s] = mn_; lo = md_; hi = mx_;                          \
    }

#define SINGLE_INSERT(d, v)                                      \
    _Pragma("unroll")                                            \
    for (int s = 0; s < KNN; ++s) {                              \
        float a_ = d[s];                                         \
        d[s] = fminf(a_, v); v = fmaxf(a_, v);                   \
    }

// ---------------------------------------------------------------------------
// K1: radius filter, owner-writes d2 AND idx. Block = 256 points x one
// 1024-cand segment (LDS-staged). No atomics; contiguous per-thread regions.
// ---------------------------------------------------------------------------
__global__ __launch_bounds__(PPB) void filter_kernel(const float* __restrict__ pts,
                                                     float* __restrict__ sd,
                                                     unsigned short* __restrict__ si,
                                                     unsigned char* __restrict__ cnt) {
    const int bx  = blockIdx.x;
    const int seg = bx % NSEG;
    const int pg  = (bx / NSEG) % PGROUPS;
    const int b   = bx / (NSEG * PGROUPS);
    const int tid = threadIdx.x;

    __shared__ float shraw[SEG * 3];            // 12 KB
    {
        const float4* src = (const float4*)(pts + ((size_t)b * NPTS + (size_t)seg * SEG) * 3);
        float4* dst = (float4*)shraw;
        #pragma unroll
        for (int i = 0; i < (SEG * 3) / 4 / PPB; ++i)   // 3 iters
            dst[tid + i * PPB] = src[tid + i * PPB];
    }
    __syncthreads();

    const int pi = pg * PPB + tid;
    const int pt = b * NPTS + pi;
    const float* pp = pts + (size_t)pt * 3;
    const float px = pp[0], py = pp[1], pz = pp[2];

    // tau(p): radius capturing ~70*1.16 expected candidates, boundary-corrected
    // via box-clip fraction, 2 fixed-point iterations + 5% safety.
    float r = R0;
    #pragma unroll
    for (int it = 0; it < 2; ++it) {
        float ex = fminf(px + r, 1.f) - fmaxf(px - r, 0.f);
        float ey = fminf(py + r, 1.f) - fmaxf(py - r, 0.f);
        float ez = fminf(pz + r, 1.f) - fmaxf(pz - r, 0.f);
        float frac = (ex * ey * ez) / (8.f * r * r * r);
        r = R0 * __powf(frac, -1.f / 3.f);
    }
    r *= 1.05f;
    const float tau = r * r;

    const int base = seg * SEG;
    float*          md = sd + ((size_t)seg * BN + pt) * CAP;
    unsigned short* mi = si + ((size_t)seg * BN + pt) * CAP;
    int count = 0;

    #pragma unroll 4
    for (int j = 0; j < SEG; ++j) {
        float cx = shraw[j * 3 + 0];
        float cy = shraw[j * 3 + 1];
        float cz = shraw[j * 3 + 2];
        float d2 = dist2s(cx, cy, cz, px, py, pz);
        if (d2 <= tau) {
            if (count < CAP) { md[count] = d2; mi[count] = (unsigned short)(base + j); }
            ++count;
        }
    }
    cnt[(size_t)seg * BN + pt] = (unsigned char)(count > 255 ? 255 : count);
}

// ---------------------------------------------------------------------------
// K2: TWO threads per point (sub=0: segs {0,1}; sub=1: segs {2,3}).
// Phase 1: each thread streams its stored d2 lists (coalesced, no gathers)
// through a gated 20-reg insert chain. Pair-merge WITHOUT re-sort: 20th
// smallest of A∪B = max_i min(A[i], B[19-i])  (bitonic merge property).
// Phase 2: masked coord-max over own survivors (idx gathers only for d2<=t),
// merged across the pair via shfl_xor. Exact full-scan fallback if any seg
// overflowed or total<20 (P ~ 1e-2 per dataset at CAP=48; exact either way).
// ---------------------------------------------------------------------------
__global__ __launch_bounds__(128) void select_kernel(const float* __restrict__ pts,
                                                     const float* __restrict__ sd,
                                                     const unsigned short* __restrict__ si,
                                                     const unsigned char* __restrict__ cnt,
                                                     float* __restrict__ feat) {
    const int gid = blockIdx.x * 128 + threadIdx.x;      // 0 .. 2*BN-1
    const int pt  = gid >> 1;
    const int sub = gid & 1;
    const int b   = pt / NPTS;
    const float* pp = pts + (size_t)pt * 3;
    const float px = pp[0], py = pp[1], pz = pp[2];
    const float* pb = pts + (size_t)b * NPTS * 3;

    int n[NSEG];
    int total = 0;
    bool ok = true;
    #pragma unroll
    for (int s = 0; s < NSEG; ++s) {
        n[s] = cnt[(size_t)s * BN + pt];
        ok = ok && (n[s] <= CAP);
        total += n[s];
    }

    float d[KNN];
    #pragma unroll
    for (int s = 0; s < KNN; ++s) d[s] = 3.4e38f;

    float gx = -3.4e38f, gy = -3.4e38f, gz = -3.4e38f;

    if (ok && total >= KNN) {
        // ---- phase 1: gated inserts over stored d2 (streaming) ----
        #pragma unroll
        for (int ss = 0; ss < 2; ++ss) {
            const int s = 2 * sub + ss;
            const float* md = sd + ((size_t)s * BN + pt) * CAP;  // 192B-aligned
            const int ns = n[s];
            int k = 0;
            for (; k + 4 <= ns; k += 4) {
                float4 v = *(const float4*)(md + k);
                float lo = fminf(v.x, v.y), hi = fmaxf(v.x, v.y);
                if (lo < d[KNN - 1]) { PAIR_INSERT(d, lo, hi) }
                lo = fminf(v.z, v.w); hi = fmaxf(v.z, v.w);
                if (lo < d[KNN - 1]) { PAIR_INSERT(d, lo, hi) }
            }
            for (; k < ns; ++k) {
                float v = md[k];
                if (v < d[KNN - 1]) { SINGLE_INSERT(d, v) }
            }
        }
        // ---- pair merge: t = 20th smallest of (mine ∪ partner) ----
        float t = -3.4e38f;
        #pragma unroll
        for (int i = 0; i < KNN; ++i) {
            float e = __shfl_xor(d[KNN - 1 - i], 1, 64);  // partner's d[19-i]
            t = fmaxf(t, fminf(d[i], e));
        }
        // ---- phase 2: masked coord-max over own survivors ----
        #pragma unroll
        for (int ss = 0; ss < 2; ++ss) {
            const int s = 2 * sub + ss;
            const float*          md = sd + ((size_t)s * BN + pt) * CAP;
            const unsigned short* mi = si + ((size_t)s * BN + pt) * CAP;
            const int ns = n[s];
            for (int k = 0; k < ns; ++k) {
                if (md[k] <= t) {
                    int j = mi[k];
                    const float* c = pb + j * 3;
                    gx = fmaxf(gx, c[0]); gy = fmaxf(gy, c[1]); gz = fmaxf(gz, c[2]);
                }
            }
        }
        gx = fmaxf(gx, __shfl_xor(gx, 1, 64));
        gy = fmaxf(gy, __shfl_xor(gy, 1, 64));
        gz = fmaxf(gz, __shfl_xor(gz, 1, 64));
    } else {
        // exact fallback: full scan (both pair threads compute identically)
        for (int j = 0; j < NPTS; j += 2) {
            const float* c0 = pb + j * 3;
            float da = dist2s(c0[0], c0[1], c0[2], px, py, pz);
            float db = dist2s(c0[3], c0[4], c0[5], px, py, pz);
            float lo = fminf(da, db), hi = fmaxf(da, db);
            PAIR_INSERT(d, lo, hi)
        }
        const float t = d[KNN - 1];
        for (int j = 0; j < NPTS; ++j) {
            const float* c = pb + j * 3;
            float d2 = dist2s(c[0], c[1], c[2], px, py, pz);
            if (d2 <= t) {
                gx = fmaxf(gx, c[0]); gy = fmaxf(gy, c[1]); gz = fmaxf(gz, c[2]);
            }
        }
    }

    if (sub == 0) {
        float* f = feat + (size_t)pt * FDIM;
        f[0] = gx - px; f[1] = gy - py; f[2] = gz - pz;
        f[3] = px; f[4] = py; f[5] = pz;
    }
}

// ---------------------------------------------------------------------------
// Trilinear corner setup, faithful to reference _corners().
// ---------------------------------------------------------------------------
__device__ __forceinline__ void corner_setup(float px, float py, float pz,
                                             int i0[3], int i1[3],
                                             float w0[3], float w1[3]) {
    float p[3] = {px, py, pz};
    #pragma unroll
    for (int d = 0; d < 3; ++d) {
        float f  = p[d] * 64.0f;
        float fl = floorf(f);
        i0[d] = (int)fl;
        i1[d] = ((int)ceilf(f)) & (RES - 1);
        float x0 = fl / 64.0f;
        float x1 = (fl + 1.0f) / 64.0f;
        w0[d] = fabsf(p[d] - x1) * 64.0f;   // corner bit == 0
        w1[d] = fabsf(p[d] - x0) * 64.0f;   // corner bit == 1
    }
}

// ---------------------------------------------------------------------------
// B: trilinear scatter-add of feat onto grid.
// ---------------------------------------------------------------------------
__global__ __launch_bounds__(256) void rasterize_kernel(const float* __restrict__ pts,
                                                        const float* __restrict__ feat,
                                                        float* __restrict__ grid) {
    int gid = blockIdx.x * 256 + threadIdx.x;            // 0 .. BN-1
    if (gid >= BN) return;
    int b = gid / NPTS;

    const float* p = pts + (size_t)gid * 3;
    float px = p[0], py = p[1], pz = p[2];

    float fv[FDIM];
    const float* f = feat + (size_t)gid * FDIM;
    #pragma unroll
    for (int c = 0; c < FDIM; ++c) fv[c] = f[c];

    int i0[3], i1[3];
    float w0[3], w1[3];
    corner_setup(px, py, pz, i0, i1, w0, w1);

    float* gb = grid + (size_t)b * RES * RES * RES * FDIM;
    #pragma unroll
    for (int c = 0; c < 8; ++c) {
        int bx = (c >> 2) & 1, by = (c >> 1) & 1, bz = c & 1;
        int ix = bx ? i1[0] : i0[0];
        int iy = by ? i1[1] : i0[1];
        int iz = bz ? i1[2] : i0[2];
        float w = (bx ? w1[0] : w0[0]) * (by ? w1[1] : w0[1]) * (bz ? w1[2] : w0[2]);
        size_t basei = ((size_t)(ix * RES + iy) * RES + iz) * FDIM;
        #pragma unroll
        for (int ch = 0; ch < FDIM; ++ch)
            atomicAdd(&gb[basei + ch], w * fv[ch]);
    }
}

// ---------------------------------------------------------------------------
// C: trilinear gather at query points.
// ---------------------------------------------------------------------------
__global__ __launch_bounds__(256) void interp_kernel(const float* __restrict__ query,
                                                     const float* __restrict__ grid,
                                                     float* __restrict__ out) {
    int gid = blockIdx.x * 256 + threadIdx.x;            // 0 .. B*NQ-1
    if (gid >= BATCH * NQ) return;
    int b = gid / NQ;

    const float* q = query + (size_t)gid * 3;
    float qx = q[0], qy = q[1], qz = q[2];

    int i0[3], i1[3];
    float w0[3], w1[3];
    corner_setup(qx, qy, qz, i0, i1, w0, w1);

    float acc[FDIM];
    #pragma unroll
    for (int ch = 0; ch < FDIM; ++ch) acc[ch] = 0.0f;

    const float* gb = grid + (size_t)b * RES * RES * RES * FDIM;
    #pragma unroll
    for (int c = 0; c < 8; ++c) {
        int bx = (c >> 2) & 1, by = (c >> 1) & 1, bz = c & 1;
        int ix = bx ? i1[0] : i0[0];
        int iy = by ? i1[1] : i0[1];
        int iz = bz ? i1[2] : i0[2];
        float w = (bx ? w1[0] : w0[0]) * (by ? w1[1] : w0[1]) * (bz ? w1[2] : w0[2]);
        const float2* g = (const float2*)(gb + ((size_t)(ix * RES + iy) * RES + iz) * FDIM);
        float2 g0 = g[0], g1 = g[1], g2 = g[2];
        acc[0] += w * g0.x; acc[1] += w * g0.y;
        acc[2] += w * g1.x; acc[3] += w * g1.y;
        acc[4] += w * g2.x; acc[5] += w * g2.y;
    }

    float* o = out + (size_t)gid * FDIM;
    #pragma unroll
    for (int ch = 0; ch < FDIM; ++ch) o[ch] = acc[ch];
}

// ---------------------------------------------------------------------------
extern "C" void kernel_launch(void* const* d_in, const int* in_sizes, int n_in,
                              void* d_out, int out_size, void* d_ws, size_t ws_size,
                              hipStream_t stream) {
    const float* pts   = (const float*)d_in[0];   // (4, 4096, 3)
    const float* query = (const float*)d_in[1];   // (4, 8192, 3)
    float* out = (float*)d_out;                   // (4, 8192, 6)

    float*          sd   = (float*)d_ws;                               // aliases grid
    unsigned short* si   = (unsigned short*)((char*)d_ws + SD_BYTES);  // aliases grid
    float*          grid = (float*)d_ws;
    unsigned char*  cnt  = (unsigned char*)((char*)d_ws + GRID_BYTES); // 64KB
    float*          feat = (float*)d_out;  // front 384KB of d_out; overwritten by interp

    filter_kernel<<<BATCH * PGROUPS * NSEG, PPB, 0, stream>>>(pts, sd, si, cnt);
    select_kernel<<<(2 * BN) / 128, 128, 0, stream>>>(pts, sd, si, cnt, feat);

    hipMemsetAsync(grid, 0, GRID_BYTES, stream);   // after select consumed sd/si alias

    rasterize_kernel<<<(BN + 255) / 256, 256, 0, stream>>>(pts, feat, grid);
    interp_kernel<<<(BATCH * NQ + 255) / 256, 256, 0, stream>>>(query, grid, out);
}

// Round 9
// 183.995 us; speedup vs baseline: 1.4338x; 1.4338x over previous
//
#include <hip/hip_runtime.h>

#define BATCH 4
#define NPTS  4096
#define NQ    8192
#define KNN   20
#define RES   64
#define FDIM  6
#define BN    (BATCH * NPTS)       // 16384 points total

#define NSEG    16                 // candidate segments per batch
#define SEG     (NPTS / NSEG)      // 256 candidates per segment
#define PPB     256                // points per block (filter)
#define PGROUPS (NPTS / PPB)       // 16

#define CAP 16                     // survivor capacity per (point, segment)
// R0 = cbrt(44 * 3 / (4096 * 4*pi)): radius targeting ~44 interior candidates;
// after 2 boundary fixed-point iters + 1.05 safety -> E[survivors] ~ 51.
#define R0 0.1368f

// ---------------- ws layout ----------------
// [0, 16.78MB)           : sd survivor d2 lists  f32 [seg][pt][CAP]  — aliases grid
// [16.78MB, 25.17MB)     : si survivor idx lists u16 [seg][pt][CAP]  — aliases grid
//   (both consumed by select BEFORE the grid memset)
// [0, GRID_BYTES)        : grid (B,64,64,64,6) after memset
// [GRID_BYTES, +256KB)   : cnt u8 [seg][pt], written unconditionally
// feat (B*NPTS*6 floats = 384KB) lives in the FRONT OF d_out: written by select,
// read by rasterize, then fully overwritten by interp's final output.
#define GRID_ELEMS ((size_t)BATCH * RES * RES * RES * FDIM)
#define GRID_BYTES (GRID_ELEMS * sizeof(float))                       // 25,165,824
#define SD_BYTES   ((size_t)NSEG * BN * CAP * sizeof(float))          // 16,777,216
#define SI_BYTES   ((size_t)NSEG * BN * CAP * sizeof(unsigned short)) //  8,388,608

__device__ __forceinline__ float dist2s(float cx, float cy, float cz,
                                        float px, float py, float pz) {
    float dx = cx - px, dy = cy - py, dz = cz - pz;
    return __builtin_fmaf(dz, dz, __builtin_fmaf(dy, dy, dx * dx));
}

// Branchless insert of pre-sorted pair (lo<=hi) into ascending 20-reg list.
#define PAIR_INSERT(d, lo, hi)                                   \
    _Pragma("unroll")                                            \
    for (int s = 0; s < KNN; ++s) {                              \
        float a_ = d[s];                                         \
        float mn_ = fminf(fminf(a_, lo), hi);                    \
        float md_ = __builtin_amdgcn_fmed3f(a_, lo, hi);         \
        float mx_ = fmaxf(fmaxf(a_, lo), hi);                    \
        d[s] = mn_; lo = md_; hi = mx_;                          \
    }

#define SINGLE_INSERT(d, v)                                      \
    _Pragma("unroll")                                            \
    for (int s = 0; s < KNN; ++s) {                              \
        float a_ = d[s];                                         \
        d[s] = fminf(a_, v); v = fmaxf(a_, v);                   \
    }

// ---------------------------------------------------------------------------
// K1: radius filter, owner-writes. Block = 256 points x one 256-cand segment
// (LDS float4-staged). 1024 blocks = 4096 waves = 4 waves/SIMD.
// ---------------------------------------------------------------------------
__global__ __launch_bounds__(PPB) void filter_kernel(const float* __restrict__ pts,
                                                     float* __restrict__ sd,
                                                     unsigned short* __restrict__ si,
                                                     unsigned char* __restrict__ cnt) {
    const int bx  = blockIdx.x;
    const int seg = bx % NSEG;
    const int pg  = (bx / NSEG) % PGROUPS;
    const int b   = bx / (NSEG * PGROUPS);
    const int tid = threadIdx.x;

    __shared__ float4 shc[SEG];                 // 4 KB
    {
        const float* src = pts + ((size_t)b * NPTS + (size_t)seg * SEG) * 3;
        shc[tid] = make_float4(src[tid * 3 + 0], src[tid * 3 + 1], src[tid * 3 + 2], 0.f);
    }
    __syncthreads();

    const int pi = pg * PPB + tid;
    const int pt = b * NPTS + pi;
    const float* pp = pts + (size_t)pt * 3;
    const float px = pp[0], py = pp[1], pz = pp[2];

    // tau(p): boundary-corrected via box-clip fraction, 2 fixed-point iters + 5%.
    float r = R0;
    #pragma unroll
    for (int it = 0; it < 2; ++it) {
        float ex = fminf(px + r, 1.f) - fmaxf(px - r, 0.f);
        float ey = fminf(py + r, 1.f) - fmaxf(py - r, 0.f);
        float ez = fminf(pz + r, 1.f) - fmaxf(pz - r, 0.f);
        float frac = (ex * ey * ez) / (8.f * r * r * r);
        r = R0 * __powf(frac, -1.f / 3.f);
    }
    r *= 1.05f;
    const float tau = r * r;

    const int base = seg * SEG;
    float*          md = sd + ((size_t)seg * BN + pt) * CAP;
    unsigned short* mi = si + ((size_t)seg * BN + pt) * CAP;
    int count = 0;

    #pragma unroll 4
    for (int j = 0; j < SEG; ++j) {
        float4 c = shc[j];
        float d2 = dist2s(c.x, c.y, c.z, px, py, pz);
        if (d2 <= tau) {
            if (count < CAP) { md[count] = d2; mi[count] = (unsigned short)(base + j); }
            ++count;
        }
    }
    cnt[(size_t)seg * BN + pt] = (unsigned char)(count > 255 ? 255 : count);
}

// ---------------------------------------------------------------------------
// K2: TWO threads per point (sub=0: segs 0..7; sub=1: segs 8..15).
// Phase 1: stream stored d2 lists (no gathers) through gated 20-reg inserts.
// Pair-merge: 20th smallest of A∪B = max_i min(A[i], B[19-i]).
// Phase 2: masked coord-max, gathers only for d2<=t; shfl_xor merges.
// Exact full-scan fallback if any seg overflowed or total<20.
// ---------------------------------------------------------------------------
__global__ __launch_bounds__(64) void select_kernel(const float* __restrict__ pts,
                                                    const float* __restrict__ sd,
                                                    const unsigned short* __restrict__ si,
                                                    const unsigned char* __restrict__ cnt,
                                                    float* __restrict__ feat) {
    const int gid = blockIdx.x * 64 + threadIdx.x;       // 0 .. 2*BN-1
    const int pt  = gid >> 1;
    const int sub = gid & 1;
    const int b   = pt / NPTS;
    const float* pp = pts + (size_t)pt * 3;
    const float px = pp[0], py = pp[1], pz = pp[2];
    const float* pb = pts + (size_t)b * NPTS * 3;

    int n[NSEG];
    int total = 0;
    bool ok = true;
    #pragma unroll
    for (int s = 0; s < NSEG; ++s) {
        n[s] = cnt[(size_t)s * BN + pt];
        ok = ok && (n[s] <= CAP);
        total += n[s];
    }

    float d[KNN];
    #pragma unroll
    for (int s = 0; s < KNN; ++s) d[s] = 3.4e38f;

    float gx = -3.4e38f, gy = -3.4e38f, gz = -3.4e38f;

    if (ok && total >= KNN) {
        // ---- phase 1: gated inserts over stored d2 (streaming) ----
        #pragma unroll
        for (int ss = 0; ss < NSEG / 2; ++ss) {
            const int s = sub * (NSEG / 2) + ss;
            const float* md = sd + ((size_t)s * BN + pt) * CAP;  // 64B-aligned
            const int ns = n[s];
            int k = 0;
            for (; k + 4 <= ns; k += 4) {
                float4 v = *(const float4*)(md + k);
                float lo = fminf(v.x, v.y), hi = fmaxf(v.x, v.y);
                if (lo < d[KNN - 1]) { PAIR_INSERT(d, lo, hi) }
                lo = fminf(v.z, v.w); hi = fmaxf(v.z, v.w);
                if (lo < d[KNN - 1]) { PAIR_INSERT(d, lo, hi) }
            }
            for (; k < ns; ++k) {
                float v = md[k];
                if (v < d[KNN - 1]) { SINGLE_INSERT(d, v) }
            }
        }
        // ---- pair merge: t = 20th smallest of (mine ∪ partner) ----
        float t = -3.4e38f;
        #pragma unroll
        for (int i = 0; i < KNN; ++i) {
            float e = __shfl_xor(d[KNN - 1 - i], 1, 64);  // partner's d[19-i]
            t = fmaxf(t, fminf(d[i], e));
        }
        // ---- phase 2: masked coord-max over own survivors ----
        #pragma unroll
        for (int ss = 0; ss < NSEG / 2; ++ss) {
            const int s = sub * (NSEG / 2) + ss;
            const float*          md = sd + ((size_t)s * BN + pt) * CAP;
            const unsigned short* mi = si + ((size_t)s * BN + pt) * CAP;
            const int ns = n[s];
            for (int k = 0; k < ns; ++k) {
                if (md[k] <= t) {
                    int j = mi[k];
                    const float* c = pb + j * 3;
                    gx = fmaxf(gx, c[0]); gy = fmaxf(gy, c[1]); gz = fmaxf(gz, c[2]);
                }
            }
        }
        gx = fmaxf(gx, __shfl_xor(gx, 1, 64));
        gy = fmaxf(gy, __shfl_xor(gy, 1, 64));
        gz = fmaxf(gz, __shfl_xor(gz, 1, 64));
    } else {
        // exact fallback: gated full scan (pair threads take this branch together)
        for (int j = 0; j < NPTS; j += 2) {
            const float* c0 = pb + j * 3;
            float da = dist2s(c0[0], c0[1], c0[2], px, py, pz);
            float db = dist2s(c0[3], c0[4], c0[5], px, py, pz);
            float lo = fminf(da, db), hi = fmaxf(da, db);
            if (lo < d[KNN - 1]) { PAIR_INSERT(d, lo, hi) }
        }
        const float t = d[KNN - 1];
        for (int j = 0; j < NPTS; ++j) {
            const float* c = pb + j * 3;
            float d2 = dist2s(c[0], c[1], c[2], px, py, pz);
            if (d2 <= t) {
                gx = fmaxf(gx, c[0]); gy = fmaxf(gy, c[1]); gz = fmaxf(gz, c[2]);
            }
        }
    }

    if (sub == 0) {
        float* f = feat + (size_t)pt * FDIM;
        f[0] = gx - px; f[1] = gy - py; f[2] = gz - pz;
        f[3] = px; f[4] = py; f[5] = pz;
    }
}

// ---------------------------------------------------------------------------
// Trilinear corner setup, faithful to reference _corners().
// ---------------------------------------------------------------------------
__device__ __forceinline__ void corner_setup(float px, float py, float pz,
                                             int i0[3], int i1[3],
                                             float w0[3], float w1[3]) {
    float p[3] = {px, py, pz};
    #pragma unroll
    for (int d = 0; d < 3; ++d) {
        float f  = p[d] * 64.0f;
        float fl = floorf(f);
        i0[d] = (int)fl;
        i1[d] = ((int)ceilf(f)) & (RES - 1);
        float x0 = fl / 64.0f;
        float x1 = (fl + 1.0f) / 64.0f;
        w0[d] = fabsf(p[d] - x1) * 64.0f;   // corner bit == 0
        w1[d] = fabsf(p[d] - x0) * 64.0f;   // corner bit == 1
    }
}

// ---------------------------------------------------------------------------
// B: trilinear scatter-add, one thread per (point, corner). 2048 waves.
// ---------------------------------------------------------------------------
__global__ __launch_bounds__(256) void rasterize_kernel(const float* __restrict__ pts,
                                                        const float* __restrict__ feat,
                                                        float* __restrict__ grid) {
    int gid = blockIdx.x * 256 + threadIdx.x;            // 0 .. BN*8-1
    int pid = gid >> 3;
    int c   = gid & 7;
    int b   = pid / NPTS;

    const float* p = pts + (size_t)pid * 3;
    float px = p[0], py = p[1], pz = p[2];

    int i0[3], i1[3];
    float w0[3], w1[3];
    corner_setup(px, py, pz, i0, i1, w0, w1);

    int bx = (c >> 2) & 1, by = (c >> 1) & 1, bz = c & 1;
    int ix = bx ? i1[0] : i0[0];
    int iy = by ? i1[1] : i0[1];
    int iz = bz ? i1[2] : i0[2];
    float w = (bx ? w1[0] : w0[0]) * (by ? w1[1] : w0[1]) * (bz ? w1[2] : w0[2]);

    const float* f = feat + (size_t)pid * FDIM;
    float* gb = grid + (size_t)b * RES * RES * RES * FDIM
                     + ((size_t)(ix * RES + iy) * RES + iz) * FDIM;
    #pragma unroll
    for (int ch = 0; ch < FDIM; ++ch)
        atomicAdd(&gb[ch], w * f[ch]);
}

// ---------------------------------------------------------------------------
// C: trilinear gather, one thread per (query, corner); shfl_xor corner-sum.
// 4096 waves, 3 float2 gathers per thread.
// ---------------------------------------------------------------------------
__global__ __launch_bounds__(256) void interp_kernel(const float* __restrict__ query,
                                                     const float* __restrict__ grid,
                                                     float* __restrict__ out) {
    int gid = blockIdx.x * 256 + threadIdx.x;            // 0 .. B*NQ*8-1
    int qid = gid >> 3;
    int c   = gid & 7;
    int b   = qid / NQ;

    const float* q = query + (size_t)qid * 3;
    float qx = q[0], qy = q[1], qz = q[2];

    int i0[3], i1[3];
    float w0[3], w1[3];
    corner_setup(qx, qy, qz, i0, i1, w0, w1);

    int bx = (c >> 2) & 1, by = (c >> 1) & 1, bz = c & 1;
    int ix = bx ? i1[0] : i0[0];
    int iy = by ? i1[1] : i0[1];
    int iz = bz ? i1[2] : i0[2];
    float w = (bx ? w1[0] : w0[0]) * (by ? w1[1] : w0[1]) * (bz ? w1[2] : w0[2]);

    const float2* g = (const float2*)(grid + (size_t)b * RES * RES * RES * FDIM
                                           + ((size_t)(ix * RES + iy) * RES + iz) * FDIM);
    float2 g0 = g[0], g1 = g[1], g2 = g[2];
    float acc[FDIM] = { w * g0.x, w * g0.y, w * g1.x, w * g1.y, w * g2.x, w * g2.y };

    #pragma unroll
    for (int delta = 1; delta < 8; delta <<= 1) {
        #pragma unroll
        for (int ch = 0; ch < FDIM; ++ch)
            acc[ch] += __shfl_xor(acc[ch], delta, 64);
    }

    if ((threadIdx.x & 7) == 0) {
        float2* o = (float2*)(out + (size_t)qid * FDIM);
        o[0] = make_float2(acc[0], acc[1]);
        o[1] = make_float2(acc[2], acc[3]);
        o[2] = make_float2(acc[4], acc[5]);
    }
}

// ---------------------------------------------------------------------------
extern "C" void kernel_launch(void* const* d_in, const int* in_sizes, int n_in,
                              void* d_out, int out_size, void* d_ws, size_t ws_size,
                              hipStream_t stream) {
    const float* pts   = (const float*)d_in[0];   // (4, 4096, 3)
    const float* query = (const float*)d_in[1];   // (4, 8192, 3)
    float* out = (float*)d_out;                   // (4, 8192, 6)

    float*          sd   = (float*)d_ws;                               // aliases grid
    unsigned short* si   = (unsigned short*)((char*)d_ws + SD_BYTES);  // aliases grid
    float*          grid = (float*)d_ws;
    unsigned char*  cnt  = (unsigned char*)((char*)d_ws + GRID_BYTES); // 256KB
    float*          feat = (float*)d_out;  // front 384KB of d_out; overwritten by interp

    filter_kernel<<<BATCH * PGROUPS * NSEG, PPB, 0, stream>>>(pts, sd, si, cnt);
    select_kernel<<<(2 * BN) / 64, 64, 0, stream>>>(pts, sd, si, cnt, feat);

    hipMemsetAsync(grid, 0, GRID_BYTES, stream);   // after select consumed sd/si alias

    rasterize_kernel<<<(BN * 8) / 256, 256, 0, stream>>>(pts, feat, grid);
    interp_kernel<<<(BATCH * NQ * 8) / 256, 256, 0, stream>>>(query, grid, out);
}

// Round 11
// 138.659 us; speedup vs baseline: 1.9026x; 1.3270x over previous
//
#include <hip/hip_runtime.h>

#define BATCH 4
#define NPTS  4096
#define NQ    8192
#define KNN   20
#define RES   64
#define FDIM  6
#define BN    (BATCH * NPTS)       // 16384 points total

#define WPB   16                   // waves (=points) per knn block
#define CAP   128                  // compacted survivor capacity per point
// R0 = cbrt(64 * 3 / (4096 * 4*pi)): radius targeting ~64 interior candidates;
// boundary fixed-point + 1.05 safety -> E[survivors] ~ 74 (tails: 6sigma to 20/128).
#define R0 0.1551f

// ---------------- ws layout ----------------
// [0, GRID_BYTES) : grid (B,64,64,64,6). No aliasing this round.
// feat (B*NPTS*6 floats = 384KB) lives in the FRONT OF d_out: written by knn,
// read by rasterize, then fully overwritten by interp's final output.
#define GRID_ELEMS ((size_t)BATCH * RES * RES * RES * FDIM)
#define GRID_BYTES (GRID_ELEMS * sizeof(float))                       // 25,165,824

__device__ __forceinline__ float dist2s(float cx, float cy, float cz,
                                        float px, float py, float pz) {
    float dx = cx - px, dy = cy - py, dz = cz - pz;
    return __builtin_fmaf(dz, dz, __builtin_fmaf(dy, dy, dx * dx));
}

// ---------------------------------------------------------------------------
// K1: fused kNN + EdgeConv feature. One WAVE per point; block = 16 waves.
// Batch coords staged in LDS once per block. Wave scans 4096 candidates,
// compacts survivors (ballot+mbcnt, wave-private -> no atomics), finds the
// exact 20th-smallest d2 via ballot binary search on float bits, then does a
// masked coord-max + shfl reduce. Exact full-set fallback, wave-uniform.
// ---------------------------------------------------------------------------
__global__ __launch_bounds__(1024) void knn_kernel(const float* __restrict__ pts,
                                                   float* __restrict__ feat) {
    __shared__ float sh[NPTS * 3];                 // 48 KB, AoS xyz
    __shared__ float cd2[WPB][CAP];                // 8 KB
    __shared__ unsigned short cidx[WPB][CAP];      // 4 KB

    const int tid  = threadIdx.x;
    const int w    = tid >> 6;
    const int lane = tid & 63;
    const int pgrp = blockIdx.x % (NPTS / WPB);    // 256 point-groups per batch
    const int b    = blockIdx.x / (NPTS / WPB);
    const int pi   = pgrp * WPB + w;
    const int pt   = b * NPTS + pi;

    {   // stage whole batch: 3072 float4s by 1024 threads
        const float4* src = (const float4*)(pts + (size_t)b * NPTS * 3);
        float4* dst = (float4*)sh;
        dst[tid]        = src[tid];
        dst[tid + 1024] = src[tid + 1024];
        dst[tid + 2048] = src[tid + 2048];
    }
    __syncthreads();

    const float px = sh[pi * 3 + 0];
    const float py = sh[pi * 3 + 1];
    const float pz = sh[pi * 3 + 2];

    // tau(p): boundary-corrected via box-clip fraction, 2 fixed-point iters + 5%.
    float r = R0;
    #pragma unroll
    for (int it = 0; it < 2; ++it) {
        float ex = fminf(px + r, 1.f) - fmaxf(px - r, 0.f);
        float ey = fminf(py + r, 1.f) - fmaxf(py - r, 0.f);
        float ez = fminf(pz + r, 1.f) - fmaxf(pz - r, 0.f);
        float frac = (ex * ey * ez) / (8.f * r * r * r);
        r = R0 * __powf(frac, -1.f / 3.f);
    }
    r *= 1.05f;
    const float tau = r * r;

    // ---- scan + wave-private compaction ----
    float*          wd2 = cd2[w];
    unsigned short* wid = cidx[w];
    int total = 0;
    for (int it = 0; it < 64; ++it) {
        const int j = (it << 6) + lane;
        float d2 = dist2s(sh[j * 3 + 0], sh[j * 3 + 1], sh[j * 3 + 2], px, py, pz);
        bool pred = d2 <= tau;
        unsigned long long m = __ballot(pred);
        int before = __builtin_amdgcn_mbcnt_hi((unsigned)(m >> 32),
                     __builtin_amdgcn_mbcnt_lo((unsigned)m, 0));
        int slot = total + before;
        if (pred && slot < CAP) { wd2[slot] = d2; wid[slot] = (unsigned short)j; }
        total += __popcll(m);
    }

    float gx = -3.4e38f, gy = -3.4e38f, gz = -3.4e38f;
    const bool ok = (total >= KNN) && (total <= CAP);

    if (ok) {
        // two compacted values per lane (inf-padded)
        unsigned u0 = (lane < total)      ? __float_as_uint(wd2[lane])      : 0x7F800000u;
        unsigned u1 = (lane + 64 < total) ? __float_as_uint(wd2[lane + 64]) : 0x7F800000u;
        // ---- ballot binary search for 20th-smallest (float bits monotonic) ----
        unsigned lo = 0u, hi = __float_as_uint(tau);
        while (lo < hi) {
            unsigned mid = (lo + hi) >> 1;
            int c = __popcll(__ballot(u0 <= mid)) + __popcll(__ballot(u1 <= mid));
            if (c >= KNN) hi = mid; else lo = mid + 1;
        }
        const unsigned tb = hi;
        // ---- masked coord-max over survivors ----
        if (u0 <= tb) {
            int j = wid[lane];
            gx = fmaxf(gx, sh[j * 3 + 0]); gy = fmaxf(gy, sh[j * 3 + 1]); gz = fmaxf(gz, sh[j * 3 + 2]);
        }
        if (u1 <= tb) {
            int j = wid[lane + 64];
            gx = fmaxf(gx, sh[j * 3 + 0]); gy = fmaxf(gy, sh[j * 3 + 1]); gz = fmaxf(gz, sh[j * 3 + 2]);
        }
    } else {
        // exact wave-parallel fallback over the full candidate set (never expected)
        unsigned lo = 0u, hi = 0x7F7FFFFFu;
        while (lo < hi) {
            unsigned mid = (lo + hi) >> 1;
            int c = 0;
            for (int it = 0; it < 64; ++it) {
                const int j = (it << 6) + lane;
                float d2 = dist2s(sh[j * 3 + 0], sh[j * 3 + 1], sh[j * 3 + 2], px, py, pz);
                c += __popcll(__ballot(__float_as_uint(d2) <= mid));
            }
            if (c >= KNN) hi = mid; else lo = mid + 1;
        }
        const unsigned tb = hi;
        for (int it = 0; it < 64; ++it) {
            const int j = (it << 6) + lane;
            float d2 = dist2s(sh[j * 3 + 0], sh[j * 3 + 1], sh[j * 3 + 2], px, py, pz);
            if (__float_as_uint(d2) <= tb) {
                gx = fmaxf(gx, sh[j * 3 + 0]); gy = fmaxf(gy, sh[j * 3 + 1]); gz = fmaxf(gz, sh[j * 3 + 2]);
            }
        }
    }

    // ---- wave max-reduce ----
    #pragma unroll
    for (int dlt = 1; dlt < 64; dlt <<= 1) {
        gx = fmaxf(gx, __shfl_xor(gx, dlt, 64));
        gy = fmaxf(gy, __shfl_xor(gy, dlt, 64));
        gz = fmaxf(gz, __shfl_xor(gz, dlt, 64));
    }

    if (lane == 0) {
        float* f = feat + (size_t)pt * FDIM;
        f[0] = gx - px; f[1] = gy - py; f[2] = gz - pz;
        f[3] = px; f[4] = py; f[5] = pz;
    }
}

// ---------------------------------------------------------------------------
// Trilinear corner setup, faithful to reference _corners().
// ---------------------------------------------------------------------------
__device__ __forceinline__ void corner_setup(float px, float py, float pz,
                                             int i0[3], int i1[3],
                                             float w0[3], float w1[3]) {
    float p[3] = {px, py, pz};
    #pragma unroll
    for (int d = 0; d < 3; ++d) {
        float f  = p[d] * 64.0f;
        float fl = floorf(f);
        i0[d] = (int)fl;
        i1[d] = ((int)ceilf(f)) & (RES - 1);
        float x0 = fl / 64.0f;
        float x1 = (fl + 1.0f) / 64.0f;
        w0[d] = fabsf(p[d] - x1) * 64.0f;   // corner bit == 0
        w1[d] = fabsf(p[d] - x0) * 64.0f;   // corner bit == 1
    }
}

// ---------------------------------------------------------------------------
// B: trilinear scatter-add, one thread per (point, corner). 2048 waves.
// ---------------------------------------------------------------------------
__global__ __launch_bounds__(256) void rasterize_kernel(const float* __restrict__ pts,
                                                        const float* __restrict__ feat,
                                                        float* __restrict__ grid) {
    int gid = blockIdx.x * 256 + threadIdx.x;            // 0 .. BN*8-1
    int pid = gid >> 3;
    int c   = gid & 7;
    int b   = pid / NPTS;

    const float* p = pts + (size_t)pid * 3;
    float px = p[0], py = p[1], pz = p[2];

    int i0[3], i1[3];
    float w0[3], w1[3];
    corner_setup(px, py, pz, i0, i1, w0, w1);

    int bx = (c >> 2) & 1, by = (c >> 1) & 1, bz = c & 1;
    int ix = bx ? i1[0] : i0[0];
    int iy = by ? i1[1] : i0[1];
    int iz = bz ? i1[2] : i0[2];
    float w = (bx ? w1[0] : w0[0]) * (by ? w1[1] : w0[1]) * (bz ? w1[2] : w0[2]);

    const float* f = feat + (size_t)pid * FDIM;
    float* gb = grid + (size_t)b * RES * RES * RES * FDIM
                     + ((size_t)(ix * RES + iy) * RES + iz) * FDIM;
    #pragma unroll
    for (int ch = 0; ch < FDIM; ++ch)
        atomicAdd(&gb[ch], w * f[ch]);
}

// ---------------------------------------------------------------------------
// C: trilinear gather, one thread per (query, corner); shfl_xor corner-sum.
// 4096 waves, 3 float2 gathers per thread.
// ---------------------------------------------------------------------------
__global__ __launch_bounds__(256) void interp_kernel(const float* __restrict__ query,
                                                     const float* __restrict__ grid,
                                                     float* __restrict__ out) {
    int gid = blockIdx.x * 256 + threadIdx.x;            // 0 .. B*NQ*8-1
    int qid = gid >> 3;
    int c   = gid & 7;
    int b   = qid / NQ;

    const float* q = query + (size_t)qid * 3;
    float qx = q[0], qy = q[1], qz = q[2];

    int i0[3], i1[3];
    float w0[3], w1[3];
    corner_setup(qx, qy, qz, i0, i1, w0, w1);

    int bx = (c >> 2) & 1, by = (c >> 1) & 1, bz = c & 1;
    int ix = bx ? i1[0] : i0[0];
    int iy = by ? i1[1] : i0[1];
    int iz = bz ? i1[2] : i0[2];
    float w = (bx ? w1[0] : w0[0]) * (by ? w1[1] : w0[1]) * (bz ? w1[2] : w0[2]);

    const float2* g = (const float2*)(grid + (size_t)b * RES * RES * RES * FDIM
                                           + ((size_t)(ix * RES + iy) * RES + iz) * FDIM);
    float2 g0 = g[0], g1 = g[1], g2 = g[2];
    float acc[FDIM] = { w * g0.x, w * g0.y, w * g1.x, w * g1.y, w * g2.x, w * g2.y };

    #pragma unroll
    for (int delta = 1; delta < 8; delta <<= 1) {
        #pragma unroll
        for (int ch = 0; ch < FDIM; ++ch)
            acc[ch] += __shfl_xor(acc[ch], delta, 64);
    }

    if ((threadIdx.x & 7) == 0) {
        float2* o = (float2*)(out + (size_t)qid * FDIM);
        o[0] = make_float2(acc[0], acc[1]);
        o[1] = make_float2(acc[2], acc[3]);
        o[2] = make_float2(acc[4], acc[5]);
    }
}

// ---------------------------------------------------------------------------
extern "C" void kernel_launch(void* const* d_in, const int* in_sizes, int n_in,
                              void* d_out, int out_size, void* d_ws, size_t ws_size,
                              hipStream_t stream) {
    const float* pts   = (const float*)d_in[0];   // (4, 4096, 3)
    const float* query = (const float*)d_in[1];   // (4, 8192, 3)
    float* out = (float*)d_out;                   // (4, 8192, 6)

    float* grid = (float*)d_ws;
    float* feat = (float*)d_out;  // front 384KB of d_out; overwritten by interp

    hipMemsetAsync(grid, 0, GRID_BYTES, stream);

    knn_kernel<<<BN / WPB, 1024, 0, stream>>>(pts, feat);

    rasterize_kernel<<<(BN * 8) / 256, 256, 0, stream>>>(pts, feat, grid);
    interp_kernel<<<(BATCH * NQ * 8) / 256, 256, 0, stream>>>(query, grid, out);
}

// Round 12
// 138.522 us; speedup vs baseline: 1.9045x; 1.0010x over previous
//
#include <hip/hip_runtime.h>

#define BATCH 4
#define NPTS  4096
#define NQ    8192
#define KNN   20
#define RES   64
#define FDIM  6
#define BN    (BATCH * NPTS)       // 16384 points total

#define WPB   16                   // waves (=points) per knn block
#define CAP   128                  // compacted survivor capacity per point
// R0 = cbrt(64 * 3 / (4096 * 4*pi)): radius targeting ~64 interior candidates;
// boundary fixed-point + 1.05 safety -> E[survivors] ~ 74 (tails: 6sigma to 20/128).
#define R0 0.1551f

// ---------------- ws layout ----------------
// [0, GRID_BYTES) : grid (B,64,64,64,6). No aliasing.
// feat (B*NPTS*6 floats = 384KB) lives in the FRONT OF d_out: written by knn,
// read by rasterize, then fully overwritten by interp's final output.
#define GRID_ELEMS ((size_t)BATCH * RES * RES * RES * FDIM)
#define GRID_BYTES (GRID_ELEMS * sizeof(float))                       // 25,165,824

__device__ __forceinline__ float dist2s(float cx, float cy, float cz,
                                        float px, float py, float pz) {
    float dx = cx - px, dy = cy - py, dz = cz - pz;
    return __builtin_fmaf(dz, dz, __builtin_fmaf(dy, dy, dx * dx));
}

__device__ __forceinline__ int mbcnt64(unsigned long long m) {
    return __builtin_amdgcn_mbcnt_hi((unsigned)(m >> 32),
           __builtin_amdgcn_mbcnt_lo((unsigned)m, 0));
}

// ---------------------------------------------------------------------------
// K1: fused kNN + EdgeConv feature. One WAVE per point; block = 16 waves.
// SoA float2 LDS scan (2 candidates/iter, conflict-free ds_read_b64), survivors
// compacted as merged (d2,idx) 8B records via branchless predicated ds_write_b64.
// Exact 20th-smallest via ballot binary search on float bits; masked coord-max;
// wave-uniform exact full-set fallback.
// ---------------------------------------------------------------------------
__global__ __launch_bounds__(1024) void knn_kernel(const float* __restrict__ pts,
                                                   float* __restrict__ feat) {
    __shared__ float sxf[NPTS];                    // 16 KB
    __shared__ float syf[NPTS];                    // 16 KB
    __shared__ float szf[NPTS];                    // 16 KB
    __shared__ uint2 went[WPB][CAP];               // 16 KB  (d2 bits, idx)
    __shared__ uint2 dump[64];                     // 512 B  (masked-lane sink)

    const int tid  = threadIdx.x;
    const int w    = tid >> 6;
    const int lane = tid & 63;
    const int pgrp = blockIdx.x % (NPTS / WPB);    // 256 point-groups per batch
    const int b    = blockIdx.x / (NPTS / WPB);
    const int pi   = pgrp * WPB + w;
    const int pt   = b * NPTS + pi;

    {   // stage batch coords, AoS global -> SoA LDS
        const float* src = pts + (size_t)b * NPTS * 3;
        for (int i = tid; i < NPTS; i += 1024) {
            sxf[i] = src[i * 3 + 0];
            syf[i] = src[i * 3 + 1];
            szf[i] = src[i * 3 + 2];
        }
    }
    __syncthreads();

    const float px = sxf[pi], py = syf[pi], pz = szf[pi];

    // tau(p): boundary-corrected via box-clip fraction, 2 fixed-point iters + 5%.
    float r = R0;
    #pragma unroll
    for (int it = 0; it < 2; ++it) {
        float ex = fminf(px + r, 1.f) - fmaxf(px - r, 0.f);
        float ey = fminf(py + r, 1.f) - fmaxf(py - r, 0.f);
        float ez = fminf(pz + r, 1.f) - fmaxf(pz - r, 0.f);
        float frac = (ex * ey * ez) / (8.f * r * r * r);
        r = R0 * __powf(frac, -1.f / 3.f);
    }
    r *= 1.05f;
    const float tau = r * r;

    // ---- scan (2 candidates/iter) + wave-private branchless compaction ----
    const float2* vx = (const float2*)sxf;
    const float2* vy = (const float2*)syf;
    const float2* vz = (const float2*)szf;
    uint2* we = went[w];
    int total = 0;

    #pragma unroll 4
    for (int it = 0; it < 32; ++it) {
        const int i2 = (it << 6) + lane;           // float2 index
        float2 cx = vx[i2], cy = vy[i2], cz = vz[i2];
        float da = dist2s(cx.x, cy.x, cz.x, px, py, pz);
        float db = dist2s(cx.y, cy.y, cz.y, px, py, pz);
        bool pa = da <= tau, pb = db <= tau;
        unsigned long long ma = __ballot(pa);
        unsigned long long mb = __ballot(pb);
        int cnta = __popcll(ma);
        int sa = total + mbcnt64(ma);
        int sb = total + cnta + mbcnt64(mb);
        uint2* aa = (pa && sa < CAP) ? &we[sa] : &dump[lane];
        *aa = make_uint2(__float_as_uint(da), (unsigned)(2 * i2));
        uint2* ab = (pb && sb < CAP) ? &we[sb] : &dump[lane];
        *ab = make_uint2(__float_as_uint(db), (unsigned)(2 * i2 + 1));
        total += cnta + __popcll(mb);
    }

    float gx = -3.4e38f, gy = -3.4e38f, gz = -3.4e38f;
    const bool ok = (total >= KNN) && (total <= CAP);

    if (ok) {
        uint2 e0 = we[lane];
        uint2 e1 = we[lane + 64];
        unsigned u0 = (lane < total)      ? e0.x : 0x7F800000u;
        unsigned u1 = (lane + 64 < total) ? e1.x : 0x7F800000u;
        // ---- ballot binary search for 20th-smallest (float bits monotonic) ----
        unsigned lo = 0u, hi = __float_as_uint(tau);
        while (lo < hi) {
            unsigned mid = (lo + hi) >> 1;
            int c = __popcll(__ballot(u0 <= mid)) + __popcll(__ballot(u1 <= mid));
            if (c >= KNN) hi = mid; else lo = mid + 1;
        }
        const unsigned tb = hi;
        // ---- masked coord-max over survivors ----
        if (u0 <= tb) {
            int j = e0.y;
            gx = fmaxf(gx, sxf[j]); gy = fmaxf(gy, syf[j]); gz = fmaxf(gz, szf[j]);
        }
        if (u1 <= tb) {
            int j = e1.y;
            gx = fmaxf(gx, sxf[j]); gy = fmaxf(gy, syf[j]); gz = fmaxf(gz, szf[j]);
        }
    } else {
        // exact wave-parallel fallback over the full candidate set (never expected)
        unsigned lo = 0u, hi = 0x7F7FFFFFu;
        while (lo < hi) {
            unsigned mid = (lo + hi) >> 1;
            int c = 0;
            for (int it = 0; it < 64; ++it) {
                const int j = (it << 6) + lane;
                float d2 = dist2s(sxf[j], syf[j], szf[j], px, py, pz);
                c += __popcll(__ballot(__float_as_uint(d2) <= mid));
            }
            if (c >= KNN) hi = mid; else lo = mid + 1;
        }
        const unsigned tb = hi;
        for (int it = 0; it < 64; ++it) {
            const int j = (it << 6) + lane;
            float d2 = dist2s(sxf[j], syf[j], szf[j], px, py, pz);
            if (__float_as_uint(d2) <= tb) {
                gx = fmaxf(gx, sxf[j]); gy = fmaxf(gy, syf[j]); gz = fmaxf(gz, szf[j]);
            }
        }
    }

    // ---- wave max-reduce ----
    #pragma unroll
    for (int dlt = 1; dlt < 64; dlt <<= 1) {
        gx = fmaxf(gx, __shfl_xor(gx, dlt, 64));
        gy = fmaxf(gy, __shfl_xor(gy, dlt, 64));
        gz = fmaxf(gz, __shfl_xor(gz, dlt, 64));
    }

    if (lane == 0) {
        float* f = feat + (size_t)pt * FDIM;
        f[0] = gx - px; f[1] = gy - py; f[2] = gz - pz;
        f[3] = px; f[4] = py; f[5] = pz;
    }
}

// ---------------------------------------------------------------------------
// Trilinear corner setup, faithful to reference _corners().
// ---------------------------------------------------------------------------
__device__ __forceinline__ void corner_setup(float px, float py, float pz,
                                             int i0[3], int i1[3],
                                             float w0[3], float w1[3]) {
    float p[3] = {px, py, pz};
    #pragma unroll
    for (int d = 0; d < 3; ++d) {
        float f  = p[d] * 64.0f;
        float fl = floorf(f);
        i0[d] = (int)fl;
        i1[d] = ((int)ceilf(f)) & (RES - 1);
        float x0 = fl / 64.0f;
        float x1 = (fl + 1.0f) / 64.0f;
        w0[d] = fabsf(p[d] - x1) * 64.0f;   // corner bit == 0
        w1[d] = fabsf(p[d] - x0) * 64.0f;   // corner bit == 1
    }
}

// ---------------------------------------------------------------------------
// B: trilinear scatter-add, one thread per (point, corner). 2048 waves.
// ---------------------------------------------------------------------------
__global__ __launch_bounds__(256) void rasterize_kernel(const float* __restrict__ pts,
                                                        const float* __restrict__ feat,
                                                        float* __restrict__ grid) {
    int gid = blockIdx.x * 256 + threadIdx.x;            // 0 .. BN*8-1
    int pid = gid >> 3;
    int c   = gid & 7;
    int b   = pid / NPTS;

    const float* p = pts + (size_t)pid * 3;
    float px = p[0], py = p[1], pz = p[2];

    int i0[3], i1[3];
    float w0[3], w1[3];
    corner_setup(px, py, pz, i0, i1, w0, w1);

    int bx = (c >> 2) & 1, by = (c >> 1) & 1, bz = c & 1;
    int ix = bx ? i1[0] : i0[0];
    int iy = by ? i1[1] : i0[1];
    int iz = bz ? i1[2] : i0[2];
    float w = (bx ? w1[0] : w0[0]) * (by ? w1[1] : w0[1]) * (bz ? w1[2] : w0[2]);

    const float* f = feat + (size_t)pid * FDIM;
    float* gb = grid + (size_t)b * RES * RES * RES * FDIM
                     + ((size_t)(ix * RES + iy) * RES + iz) * FDIM;
    #pragma unroll
    for (int ch = 0; ch < FDIM; ++ch)
        atomicAdd(&gb[ch], w * f[ch]);
}

// ---------------------------------------------------------------------------
// C: trilinear gather, one thread per (query, corner); shfl_xor corner-sum.
// 4096 waves, 3 float2 gathers per thread.
// ---------------------------------------------------------------------------
__global__ __launch_bounds__(256) void interp_kernel(const float* __restrict__ query,
                                                     const float* __restrict__ grid,
                                                     float* __restrict__ out) {
    int gid = blockIdx.x * 256 + threadIdx.x;            // 0 .. B*NQ*8-1
    int qid = gid >> 3;
    int c   = gid & 7;
    int b   = qid / NQ;

    const float* q = query + (size_t)qid * 3;
    float qx = q[0], qy = q[1], qz = q[2];

    int i0[3], i1[3];
    float w0[3], w1[3];
    corner_setup(qx, qy, qz, i0, i1, w0, w1);

    int bx = (c >> 2) & 1, by = (c >> 1) & 1, bz = c & 1;
    int ix = bx ? i1[0] : i0[0];
    int iy = by ? i1[1] : i0[1];
    int iz = bz ? i1[2] : i0[2];
    float w = (bx ? w1[0] : w0[0]) * (by ? w1[1] : w0[1]) * (bz ? w1[2] : w0[2]);

    const float2* g = (const float2*)(grid + (size_t)b * RES * RES * RES * FDIM
                                           + ((size_t)(ix * RES + iy) * RES + iz) * FDIM);
    float2 g0 = g[0], g1 = g[1], g2 = g[2];
    float acc[FDIM] = { w * g0.x, w * g0.y, w * g1.x, w * g1.y, w * g2.x, w * g2.y };

    #pragma unroll
    for (int delta = 1; delta < 8; delta <<= 1) {
        #pragma unroll
        for (int ch = 0; ch < FDIM; ++ch)
            acc[ch] += __shfl_xor(acc[ch], delta, 64);
    }

    if ((threadIdx.x & 7) == 0) {
        float2* o = (float2*)(out + (size_t)qid * FDIM);
        o[0] = make_float2(acc[0], acc[1]);
        o[1] = make_float2(acc[2], acc[3]);
        o[2] = make_float2(acc[4], acc[5]);
    }
}

// ---------------------------------------------------------------------------
extern "C" void kernel_launch(void* const* d_in, const int* in_sizes, int n_in,
                              void* d_out, int out_size, void* d_ws, size_t ws_size,
                              hipStream_t stream) {
    const float* pts   = (const float*)d_in[0];   // (4, 4096, 3)
    const float* query = (const float*)d_in[1];   // (4, 8192, 3)
    float* out = (float*)d_out;                   // (4, 8192, 6)

    float* grid = (float*)d_ws;
    float* feat = (float*)d_out;  // front 384KB of d_out; overwritten by interp

    hipMemsetAsync(grid, 0, GRID_BYTES, stream);

    knn_kernel<<<BN / WPB, 1024, 0, stream>>>(pts, feat);

    rasterize_kernel<<<(BN * 8) / 256, 256, 0, stream>>>(pts, feat, grid);
    interp_kernel<<<(BATCH * NQ * 8) / 256, 256, 0, stream>>>(query, grid, out);
}